// Round 5
// baseline (520.262 us; speedup 1.0000x reference)
//
#include <hip/hip_runtime.h>
#include <stdint.h>

// 256-col output tiles, BK=32, double-buffered LDS, 512-thread blocks (8 waves, 2x4).
// MI = A-row frags per wave: MI=8 -> BM=256 (64KB LDS), MI=4 -> BM=128 (48KB LDS).

typedef _Float16 f16;
typedef __attribute__((ext_vector_type(8))) _Float16 f16x8;
typedef __attribute__((ext_vector_type(4))) _Float16 f16x4;
typedef __attribute__((ext_vector_type(4))) float floatx4;

static __device__ __forceinline__ void async_load16(const void* g, void* l) {
    __builtin_amdgcn_global_load_lds(
        (const __attribute__((address_space(1))) unsigned int*)g,
        (__attribute__((address_space(3))) unsigned int*)l, 16, 0, 0);
}

// Stage a ROWSx32 f16 tile (row-major, ld elems) into LDS [4 kblk][ROWS][8].
// 16B chunk c <-> (kblk = c>>log2(ROWS), m = c&(ROWS-1)). 512 threads.
template <int ROWS>
static __device__ __forceinline__ void stage_tile(const f16* src, int ld, f16* lds, int tid) {
    constexpr int NT = ROWS / 128;          // chunks per thread (ROWS*4 / 512)
    constexpr int SH = (ROWS == 256) ? 8 : 7;
    int lane = tid & 63;
#pragma unroll
    for (int t = 0; t < NT; ++t) {
        int base = (tid >> 6) * 64 + t * 512;   // wave-uniform
        int c = base + lane;
        int m = c & (ROWS - 1), kb = c >> SH;   // kb wave-uniform (base mult of 64)
        const f16* gp = src + (size_t)m * ld + kb * 8;
        f16* lp = lds + ((size_t)((base >> SH) * ROWS + (base & (ROWS - 1)))) * 8;
        async_load16(gp, lp);
    }
}

// CMODE: 0 = fp32 out (+bias), 1 = f16 out (+bias), 3 = f16 transposed vT out (+bias)
template <int MI, int CMODE>
static __device__ __forceinline__ void gemm_body(
    f16* smem,
    const f16* Ap, int lda, long long a_zoff,
    const f16* Bp, int ldb, long long b_zoff,
    void* Cp, int ldc, long long c_zoff,
    const float* bias, int K, int z)
{
    constexpr int BMv = MI * 32;
    constexpr int AT = BMv * 32;   // f16 elems per A tile
    constexpr int BT = 256 * 32;

    int tid = threadIdx.x;
    int lane = tid & 63;
    int wid = tid >> 6;           // 0..7
    int wm = wid >> 2;            // 0..1
    int wn = wid & 3;             // 0..3
    size_t row0 = (size_t)blockIdx.y * BMv;
    size_t col0 = (size_t)blockIdx.x * 256;

    floatx4 acc[MI][4];
#pragma unroll
    for (int i = 0; i < MI; ++i)
#pragma unroll
        for (int j = 0; j < 4; ++j) acc[i][j] = floatx4{0.f, 0.f, 0.f, 0.f};

    const f16* a0 = Ap + (size_t)z * a_zoff + row0 * lda;
    const f16* b0 = Bp + (size_t)z * b_zoff + col0 * ldb;

    int quad = lane >> 4, mr = lane & 15;

    // prologue: stage first K-chunk into buffer 0
    stage_tile<BMv>(a0, lda, smem, tid);
    stage_tile<256>(b0, ldb, smem + 2 * AT, tid);
    __syncthreads();

    int cur = 0;
    for (int k0 = 0; k0 < K; k0 += 32) {
        f16* Ac = smem + cur * AT;
        f16* Bc = smem + 2 * AT + cur * BT;
        if (k0 + 32 < K) {  // stage next chunk into the other buffer (async, overlaps MFMA)
            stage_tile<BMv>(a0 + k0 + 32, lda, smem + (cur ^ 1) * AT, tid);
            stage_tile<256>(b0 + k0 + 32, ldb, smem + 2 * AT + (cur ^ 1) * BT, tid);
        }

        f16x8 ah[MI];
#pragma unroll
        for (int i = 0; i < MI; ++i)
            ah[i] = *(const f16x8*)(Ac + ((quad * BMv + wm * (MI * 16) + i * 16 + mr)) * 8);
#pragma unroll
        for (int j = 0; j < 4; ++j) {
            f16x8 bh = *(const f16x8*)(Bc + ((quad * 256 + wn * 64 + j * 16 + mr)) * 8);
#pragma unroll
            for (int i = 0; i < MI; ++i)
                acc[i][j] = __builtin_amdgcn_mfma_f32_16x16x32_f16(ah[i], bh, acc[i][j], 0, 0, 0);
        }
        __syncthreads();  // drains vmcnt(0): next buffer ready; all reads of cur done
        cur ^= 1;
    }

#pragma unroll
    for (int i = 0; i < MI; ++i) {
#pragma unroll
        for (int j = 0; j < 4; ++j) {
#pragma unroll
            for (int r = 0; r < 4; ++r) {
                size_t rr = row0 + (size_t)(wm * (MI * 16) + i * 16 + quad * 4 + r);
                size_t cc = col0 + (size_t)(wn * 64 + j * 16 + mr);
                float v = acc[i][j][r];
                if (bias) v += bias[cc];
                if constexpr (CMODE == 0) {
                    float* C = (float*)Cp + (size_t)z * c_zoff;
                    C[rr * ldc + cc] = v;
                } else if constexpr (CMODE == 1) {
                    f16* C = (f16*)Cp + (size_t)z * c_zoff;
                    C[rr * ldc + cc] = (f16)v;
                } else {  // vT[b][col][s]: b = rr>>11, s = rr&2047, col dim 1024
                    f16* C = (f16*)Cp;
                    size_t b = rr >> 11, s = rr & 2047;
                    C[((b << 10) + cc) * 2048 + s] = (f16)v;
                }
            }
        }
    }
}

// Merged q/k/v projection (BM=256): z selects input, weight, bias, output mode.
__global__ __launch_bounds__(512, 2) void g_qkv(const f16* x, const f16* W,
                                                f16* qk, f16* vT,
                                                const float* bq, const float* bk,
                                                const float* bv, int D, long long ten) {
    __shared__ __align__(16) f16 smem[2 * (256 * 32 + 256 * 32)];  // 64 KB
    int z = blockIdx.z;
    const float* bias = (z == 0) ? bq : (z == 1) ? bk : bv;
    if (z < 2) {
        gemm_body<8, 1>(smem, x + (size_t)z * ten, D, 0, W + (size_t)z * D * D, D, 0,
                        qk + (size_t)z * ten, D, 0, bias, D, 0);
    } else {
        gemm_body<8, 3>(smem, x + (size_t)2 * ten, D, 0, W + (size_t)2 * D * D, D, 0,
                        vT, 0, 0, bias, D, 0);
    }
}
__global__ __launch_bounds__(512, 2) void g_scores(const f16* A, int lda, long long az,
                                                   const f16* B, int ldb, long long bz,
                                                   float* C, int ldc, long long cz, int K) {
    __shared__ __align__(16) f16 smem[2 * (256 * 32 + 256 * 32)];  // 64 KB
    gemm_body<8, 0>(smem, A, lda, az, B, ldb, bz, C, ldc, cz, nullptr, K, blockIdx.z);
}
__global__ __launch_bounds__(512, 2) void g_attnv(const f16* A, int lda, long long az,
                                                  const f16* B, int ldb, long long bz,
                                                  f16* C, int ldc, long long cz, int K) {
    __shared__ __align__(16) f16 smem[2 * (128 * 32 + 256 * 32)];  // 48 KB
    gemm_body<4, 1>(smem, A, lda, az, B, ldb, bz, C, ldc, cz, nullptr, K, blockIdx.z);
}
__global__ __launch_bounds__(512, 2) void g_out(const f16* A, int lda, const f16* B, int ldb,
                                                float* C, int ldc, const float* bias, int K) {
    __shared__ __align__(16) f16 smem[2 * (128 * 32 + 256 * 32)];  // 48 KB
    gemm_body<4, 0>(smem, A, lda, 0, B, ldb, 0, C, ldc, 0, bias, K, 0);
}

// fp32 -> fp16 convert for q/k/v in one dispatch; dst = [xq|xk|xv] contiguous.
__global__ __launch_bounds__(256) void cvt_f16(const float* q, const float* k, const float* v,
                                               f16* dst, long long ten) {
    int z = blockIdx.y;
    const float* src = (z == 0) ? q : (z == 1) ? k : v;
    size_t i = ((size_t)blockIdx.x * 256 + threadIdx.x) * 4;
    float4 x = *(const float4*)(src + i);
    f16x4 h = {(f16)x.x, (f16)x.y, (f16)x.z, (f16)x.w};
    *(f16x4*)(dst + (size_t)z * ten + i) = h;
}

// All four weight transposes in one dispatch; T = [WqT|WkT|WvT|WdT] contiguous.
__global__ __launch_bounds__(256) void wtrans(const float* Wq, const float* Wk,
                                              const float* Wv, const float* Wd,
                                              f16* T, int n) {
    __shared__ float tile[32][33];
    int z = blockIdx.z;
    const float* W = (z == 0) ? Wq : (z == 1) ? Wk : (z == 2) ? Wv : Wd;
    f16* Tz = T + (size_t)z * n * n;
    int bx = blockIdx.x * 32;
    int by = blockIdx.y * 32;
    int tx = threadIdx.x & 31;
    int ty = threadIdx.x >> 5;
    for (int r = ty; r < 32; r += 8) tile[r][tx] = W[(size_t)(by + r) * n + bx + tx];
    __syncthreads();
    for (int r = ty; r < 32; r += 8) Tz[(size_t)(bx + r) * n + by + tx] = (f16)tile[tx][r];
}

// One block per row of 2048 fp32 logits; writes fp16 attn into the first half
// of the same row's storage (row byte stride stays 8192 => f16 lda 4096).
__global__ __launch_bounds__(256) void softmax_k(float* scores) {
    size_t row = blockIdx.x;
    float* rp = scores + row * 2048;
    int tid = threadIdx.x;
    int lane = tid & 63, w = tid >> 6;
    float x[8];
    float mx = -3.4e38f;
#pragma unroll
    for (int i = 0; i < 8; ++i) {
        x[i] = rp[tid + i * 256];
        mx = fmaxf(mx, x[i]);
    }
#pragma unroll
    for (int o = 32; o > 0; o >>= 1) mx = fmaxf(mx, __shfl_xor(mx, o, 64));
    __shared__ float redm[4];
    __shared__ float reds[4];
    if (lane == 0) redm[w] = mx;
    __syncthreads();  // also orders: all row reads complete before any write below
    mx = fmaxf(fmaxf(redm[0], redm[1]), fmaxf(redm[2], redm[3]));
    float s = 0.f;
#pragma unroll
    for (int i = 0; i < 8; ++i) {
        x[i] = __expf(x[i] - mx);
        s += x[i];
    }
#pragma unroll
    for (int o = 32; o > 0; o >>= 1) s += __shfl_xor(s, o, 64);
    if (lane == 0) reds[w] = s;
    __syncthreads();
    s = reds[0] + reds[1] + reds[2] + reds[3];
    float inv = 1.f / s;
    f16* op = (f16*)rp;
#pragma unroll
    for (int i = 0; i < 8; ++i) op[tid + i * 256] = (f16)(x[i] * inv);
}

extern "C" void kernel_launch(void* const* d_in, const int* in_sizes, int n_in,
                              void* d_out, int out_size, void* d_ws, size_t ws_size,
                              hipStream_t stream) {
    const float* query  = (const float*)d_in[0];
    const float* keys   = (const float*)d_in[1];
    const float* values = (const float*)d_in[2];
    const float* Wq = (const float*)d_in[3];
    const float* bq = (const float*)d_in[4];
    const float* Wk = (const float*)d_in[5];
    const float* bk = (const float*)d_in[6];
    const float* Wv = (const float*)d_in[7];
    const float* bv = (const float*)d_in[8];
    const float* Wd = (const float*)d_in[9];
    const float* bd = (const float*)d_in[10];
    float* out = (float*)d_out;

    const int S = 2048, D = 1024, NB = 4;
    const size_t TEN = (size_t)NB * S * D;  // 8.39M, TEN*2 bytes is 256-aligned

    char* p = (char*)d_ws;
    auto alloc = [&](size_t bytes) {
        char* r = p;
        p += (bytes + 255) & ~(size_t)255;
        return r;
    };
    f16* x3  = (f16*)alloc(TEN * 2 * 3);   // [xq|xk|xv]
    f16* q16 = (f16*)alloc(TEN * 2 * 2);   // [q16|k16]
    f16* k16 = q16 + TEN;
    f16* vT  = (f16*)alloc(TEN * 2);
    f16* WT  = (f16*)alloc((size_t)D * D * 2 * 4);  // [WqT|WkT|WvT|WdT]
    float* scores = (float*)p;
    long long avail = (long long)ws_size - (long long)(p - (char*)d_ws);
    long long sbytes = (long long)S * S * 4;
    int g = (avail >= 4 * sbytes) ? 4 : (avail >= 2 * sbytes) ? 2 : 1;
    f16* att = x3;  // alias: x3 is dead after the qkv projections

    dim3 blk256(256), blk512(512);
    cvt_f16<<<dim3((unsigned)(TEN / 1024), 3), blk256, 0, stream>>>(query, keys, values, x3, TEN);
    wtrans<<<dim3(D / 32, D / 32, 4), blk256, 0, stream>>>(Wq, Wk, Wv, Wd, WT, D);

    // qkv: BM=256, BN=256 -> grid (4, 32, 3) = 384 blocks
    g_qkv<<<dim3(D / 256, (NB * S) / 256, 3), blk512, 0, stream>>>(
        x3, WT, q16, vT, bq, bk, bv, D, (long long)TEN);

    for (int g0 = 0; g0 < NB; g0 += g) {
        int gz = (NB - g0 < g) ? (NB - g0) : g;
        // scores: BM=BN=256 -> (8, 8, gz)
        g_scores<<<dim3(S / 256, S / 256, gz), blk512, 0, stream>>>(
            q16 + (size_t)g0 * S * D, D, (long long)S * D,
            k16 + (size_t)g0 * S * D, D, (long long)S * D,
            scores, S, (long long)S * S, D);
        softmax_k<<<dim3((unsigned)(gz * S)), blk256, 0, stream>>>(scores);
        // attnv: BM=128, BN=256 -> (4, 16, gz), K = S
        g_attnv<<<dim3(D / 256, S / 128, gz), blk512, 0, stream>>>(
            (const f16*)scores, 2 * S, (long long)S * 2 * S,
            vT + (size_t)g0 * D * S, S, (long long)D * S,
            att + (size_t)g0 * S * D, D, (long long)S * D, S);
    }

    // out: BM=128, BN=256 -> (4, 64) = 256 blocks
    g_out<<<dim3(D / 256, (NB * S) / 128, 1), blk512, 0, stream>>>(
        att, D, WT + (size_t)3 * D * D, D, out, D, bd, D);
}

// Round 6
// 510.813 us; speedup vs baseline: 1.0185x; 1.0185x over previous
//
#include <hip/hip_runtime.h>
#include <stdint.h>

// Asymmetric tiles, 256-thread blocks (4 waves, 2x2 wave grid).
// MI=8: BM=256, wave-tile 128x64, BK=32, LDS 24 KB (qkv, scores).
// MI=4: BM=128, wave-tile 64x64,  BK=64, LDS 32 KB (attnv, out).
// BN=128 everywhere. Single-buffered staging via global_load_lds width=16.

typedef _Float16 f16;
typedef __attribute__((ext_vector_type(8))) _Float16 f16x8;
typedef __attribute__((ext_vector_type(4))) _Float16 f16x4;
typedef __attribute__((ext_vector_type(4))) float floatx4;

static __device__ __forceinline__ void async_load16(const void* g, void* l) {
    __builtin_amdgcn_global_load_lds(
        (const __attribute__((address_space(1))) unsigned int*)g,
        (__attribute__((address_space(3))) unsigned int*)l, 16, 0, 0);
}

// Stage a ROWSxBK f16 tile (row-major, ld elems) into LDS [BK/8][ROWS][8].
// 16B chunk c <-> (kb = c>>log2(ROWS), m = c&(ROWS-1)). 256 threads.
template <int ROWS, int BKv>
static __device__ __forceinline__ void stage_tile(const f16* src, int ld, f16* lds, int tid) {
    constexpr int NT = (ROWS * BKv / 8) / 256;  // 16B chunks per thread
    constexpr int SH = (ROWS == 256) ? 8 : 7;
    int lane = tid & 63;
#pragma unroll
    for (int t = 0; t < NT; ++t) {
        int base = (tid >> 6) * 64 + t * 256;   // wave-uniform, multiple of 64
        int c = base + lane;
        int m = c & (ROWS - 1), kb = c >> SH;   // kb uniform within wave-chunk
        const f16* gp = src + (size_t)m * ld + kb * 8;
        f16* lp = lds + (size_t)((base >> SH) * ROWS + (base & (ROWS - 1))) * 8;
        async_load16(gp, lp);
    }
}

// CMODE: 0 = fp32 out (+bias), 1 = f16 out (+bias), 3 = f16 transposed vT out (+bias)
template <int MI, int NKB, int CMODE>
static __device__ __forceinline__ void gemm_body(
    f16* As, f16* Bs,
    const f16* Ap, int lda, long long a_zoff,
    const f16* Bp, int ldb, long long b_zoff,
    void* Cp, int ldc, long long c_zoff,
    const float* bias, int K, int z)
{
    constexpr int BMv = MI * 32;   // 2 row wave-groups of MI*16
    constexpr int BKv = NKB * 32;

    int tid = threadIdx.x;
    int lane = tid & 63;
    int wid = tid >> 6;           // 0..3
    int wm = wid >> 1, wn = wid & 1;
    size_t row0 = (size_t)blockIdx.y * BMv;
    size_t col0 = (size_t)blockIdx.x * 128;

    floatx4 acc[MI][4];
#pragma unroll
    for (int i = 0; i < MI; ++i)
#pragma unroll
        for (int j = 0; j < 4; ++j) acc[i][j] = floatx4{0.f, 0.f, 0.f, 0.f};

    const f16* a0 = Ap + (size_t)z * a_zoff + row0 * lda;
    const f16* b0 = Bp + (size_t)z * b_zoff + col0 * ldb;

    int quad = lane >> 4, mr = lane & 15;

    for (int k0 = 0; k0 < K; k0 += BKv) {
        __syncthreads();
        stage_tile<BMv, BKv>(a0 + k0, lda, As, tid);
        stage_tile<128, BKv>(b0 + k0, ldb, Bs, tid);
        __syncthreads();

#pragma unroll
        for (int s = 0; s < NKB; ++s) {
            f16x8 ah[MI];
#pragma unroll
            for (int i = 0; i < MI; ++i)
                ah[i] = *(const f16x8*)(As + (size_t)((s * 4 + quad) * BMv + wm * (MI * 16) + i * 16 + mr) * 8);
#pragma unroll
            for (int j = 0; j < 4; ++j) {
                f16x8 bh = *(const f16x8*)(Bs + (size_t)((s * 4 + quad) * 128 + wn * 64 + j * 16 + mr) * 8);
#pragma unroll
                for (int i = 0; i < MI; ++i)
                    acc[i][j] = __builtin_amdgcn_mfma_f32_16x16x32_f16(ah[i], bh, acc[i][j], 0, 0, 0);
            }
        }
    }

#pragma unroll
    for (int i = 0; i < MI; ++i) {
#pragma unroll
        for (int j = 0; j < 4; ++j) {
#pragma unroll
            for (int r = 0; r < 4; ++r) {
                size_t rr = row0 + (size_t)(wm * (MI * 16) + i * 16 + quad * 4 + r);
                size_t cc = col0 + (size_t)(wn * 64 + j * 16 + mr);
                float v = acc[i][j][r];
                if (bias) v += bias[cc];
                if constexpr (CMODE == 0) {
                    float* C = (float*)Cp + (size_t)z * c_zoff;
                    C[rr * ldc + cc] = v;
                } else if constexpr (CMODE == 1) {
                    f16* C = (f16*)Cp + (size_t)z * c_zoff;
                    C[rr * ldc + cc] = (f16)v;
                } else {  // vT[b][col][s]: b = rr>>11, s = rr&2047, col dim 1024
                    f16* C = (f16*)Cp;
                    size_t b = rr >> 11, s = rr & 2047;
                    C[((b << 10) + cc) * 2048 + s] = (f16)v;
                }
            }
        }
    }
}

// Merged q/k/v projection (BM=256, BK=32): z selects input/weight/bias/output mode.
__global__ __launch_bounds__(256, 2) void g_qkv(const f16* x, const f16* W,
                                                f16* qk, f16* vT,
                                                const float* bq, const float* bk,
                                                const float* bv, int D, long long ten) {
    __shared__ __align__(16) f16 smem[256 * 32 + 128 * 32];  // 24 KB
    f16* As = smem;
    f16* Bs = smem + 256 * 32;
    int z = blockIdx.z;
    const float* bias = (z == 0) ? bq : (z == 1) ? bk : bv;
    if (z < 2) {
        gemm_body<8, 1, 1>(As, Bs, x + (size_t)z * ten, D, 0, W + (size_t)z * D * D, D, 0,
                           qk + (size_t)z * ten, D, 0, bias, D, 0);
    } else {
        gemm_body<8, 1, 3>(As, Bs, x + (size_t)2 * ten, D, 0, W + (size_t)2 * D * D, D, 0,
                           vT, 0, 0, bias, D, 0);
    }
}
__global__ __launch_bounds__(256, 2) void g_scores(const f16* A, int lda, long long az,
                                                   const f16* B, int ldb, long long bz,
                                                   float* C, int ldc, long long cz, int K) {
    __shared__ __align__(16) f16 smem[256 * 32 + 128 * 32];  // 24 KB
    gemm_body<8, 1, 0>(smem, smem + 256 * 32, A, lda, az, B, ldb, bz, C, ldc, cz, nullptr, K,
                       blockIdx.z);
}
__global__ __launch_bounds__(256, 2) void g_attnv(const f16* A, int lda, long long az,
                                                  const f16* B, int ldb, long long bz,
                                                  f16* C, int ldc, long long cz, int K) {
    __shared__ __align__(16) f16 smem[128 * 64 + 128 * 64];  // 32 KB
    gemm_body<4, 2, 1>(smem, smem + 128 * 64, A, lda, az, B, ldb, bz, C, ldc, cz, nullptr, K,
                       blockIdx.z);
}
__global__ __launch_bounds__(256, 2) void g_out(const f16* A, int lda, const f16* B, int ldb,
                                                float* C, int ldc, const float* bias, int K) {
    __shared__ __align__(16) f16 smem[128 * 64 + 128 * 64];  // 32 KB
    gemm_body<4, 2, 0>(smem, smem + 128 * 64, A, lda, 0, B, ldb, 0, C, ldc, 0, bias, K, 0);
}

// fp32 -> fp16 convert for q/k/v in one dispatch; dst = [xq|xk|xv] contiguous.
__global__ __launch_bounds__(256) void cvt_f16(const float* q, const float* k, const float* v,
                                               f16* dst, long long ten) {
    int z = blockIdx.y;
    const float* src = (z == 0) ? q : (z == 1) ? k : v;
    size_t i = ((size_t)blockIdx.x * 256 + threadIdx.x) * 4;
    float4 x = *(const float4*)(src + i);
    f16x4 h = {(f16)x.x, (f16)x.y, (f16)x.z, (f16)x.w};
    *(f16x4*)(dst + (size_t)z * ten + i) = h;
}

// All four weight transposes in one dispatch; T = [WqT|WkT|WvT|WdT] contiguous.
__global__ __launch_bounds__(256) void wtrans(const float* Wq, const float* Wk,
                                              const float* Wv, const float* Wd,
                                              f16* T, int n) {
    __shared__ float tile[32][33];
    int z = blockIdx.z;
    const float* W = (z == 0) ? Wq : (z == 1) ? Wk : (z == 2) ? Wv : Wd;
    f16* Tz = T + (size_t)z * n * n;
    int bx = blockIdx.x * 32;
    int by = blockIdx.y * 32;
    int tx = threadIdx.x & 31;
    int ty = threadIdx.x >> 5;
    for (int r = ty; r < 32; r += 8) tile[r][tx] = W[(size_t)(by + r) * n + bx + tx];
    __syncthreads();
    for (int r = ty; r < 32; r += 8) Tz[(size_t)(bx + r) * n + by + tx] = (f16)tile[tx][r];
}

// One block per row of 2048 fp32 logits; writes fp16 attn into the first half
// of the same row's storage (row byte stride stays 8192 => f16 lda 4096).
__global__ __launch_bounds__(256) void softmax_k(float* scores) {
    size_t row = blockIdx.x;
    float* rp = scores + row * 2048;
    int tid = threadIdx.x;
    int lane = tid & 63, w = tid >> 6;
    float x[8];
    float mx = -3.4e38f;
#pragma unroll
    for (int i = 0; i < 8; ++i) {
        x[i] = rp[tid + i * 256];
        mx = fmaxf(mx, x[i]);
    }
#pragma unroll
    for (int o = 32; o > 0; o >>= 1) mx = fmaxf(mx, __shfl_xor(mx, o, 64));
    __shared__ float redm[4];
    __shared__ float reds[4];
    if (lane == 0) redm[w] = mx;
    __syncthreads();  // also orders: all row reads complete before any write below
    mx = fmaxf(fmaxf(redm[0], redm[1]), fmaxf(redm[2], redm[3]));
    float s = 0.f;
#pragma unroll
    for (int i = 0; i < 8; ++i) {
        x[i] = __expf(x[i] - mx);
        s += x[i];
    }
#pragma unroll
    for (int o = 32; o > 0; o >>= 1) s += __shfl_xor(s, o, 64);
    if (lane == 0) reds[w] = s;
    __syncthreads();
    s = reds[0] + reds[1] + reds[2] + reds[3];
    float inv = 1.f / s;
    f16* op = (f16*)rp;
#pragma unroll
    for (int i = 0; i < 8; ++i) op[tid + i * 256] = (f16)(x[i] * inv);
}

extern "C" void kernel_launch(void* const* d_in, const int* in_sizes, int n_in,
                              void* d_out, int out_size, void* d_ws, size_t ws_size,
                              hipStream_t stream) {
    const float* query  = (const float*)d_in[0];
    const float* keys   = (const float*)d_in[1];
    const float* values = (const float*)d_in[2];
    const float* Wq = (const float*)d_in[3];
    const float* bq = (const float*)d_in[4];
    const float* Wk = (const float*)d_in[5];
    const float* bk = (const float*)d_in[6];
    const float* Wv = (const float*)d_in[7];
    const float* bv = (const float*)d_in[8];
    const float* Wd = (const float*)d_in[9];
    const float* bd = (const float*)d_in[10];
    float* out = (float*)d_out;

    const int S = 2048, D = 1024, NB = 4;
    const size_t TEN = (size_t)NB * S * D;  // 8.39M, TEN*2 bytes is 256-aligned

    char* p = (char*)d_ws;
    auto alloc = [&](size_t bytes) {
        char* r = p;
        p += (bytes + 255) & ~(size_t)255;
        return r;
    };
    f16* x3  = (f16*)alloc(TEN * 2 * 3);   // [xq|xk|xv]
    f16* q16 = (f16*)alloc(TEN * 2 * 2);   // [q16|k16]
    f16* k16 = q16 + TEN;
    f16* vT  = (f16*)alloc(TEN * 2);
    f16* WT  = (f16*)alloc((size_t)D * D * 2 * 4);  // [WqT|WkT|WvT|WdT]
    float* scores = (float*)p;
    long long avail = (long long)ws_size - (long long)(p - (char*)d_ws);
    long long sbytes = (long long)S * S * 4;
    int g = (avail >= 4 * sbytes) ? 4 : (avail >= 2 * sbytes) ? 2 : 1;
    f16* att = x3;  // alias: x3 is dead after the qkv projections

    dim3 blk(256);
    cvt_f16<<<dim3((unsigned)(TEN / 1024), 3), blk, 0, stream>>>(query, keys, values, x3, TEN);
    wtrans<<<dim3(D / 32, D / 32, 4), blk, 0, stream>>>(Wq, Wk, Wv, Wd, WT, D);

    // qkv: BM=256, BN=128 -> grid (8, 32, 3) = 768 blocks (3/CU)
    g_qkv<<<dim3(D / 128, (NB * S) / 256, 3), blk, 0, stream>>>(
        x3, WT, q16, vT, bq, bk, bv, D, (long long)TEN);

    for (int g0 = 0; g0 < NB; g0 += g) {
        int gz = (NB - g0 < g) ? (NB - g0) : g;
        // scores: BM=256, BN=128 -> (16, 8, gz)
        g_scores<<<dim3(S / 128, S / 256, gz), blk, 0, stream>>>(
            q16 + (size_t)g0 * S * D, D, (long long)S * D,
            k16 + (size_t)g0 * S * D, D, (long long)S * D,
            scores, S, (long long)S * S, D);
        softmax_k<<<dim3((unsigned)(gz * S)), blk, 0, stream>>>(scores);
        // attnv: BM=128, BN=128, BK=64 -> (8, 16, gz), K = S
        g_attnv<<<dim3(D / 128, S / 128, gz), blk, 0, stream>>>(
            (const f16*)scores, 2 * S, (long long)S * 2 * S,
            vT + (size_t)g0 * D * S, S, (long long)D * S,
            att + (size_t)g0 * S * D, D, (long long)S * D, S);
    }

    // out: BM=128, BN=128, BK=64 -> (8, 64) = 512 blocks
    g_out<<<dim3(D / 128, (NB * S) / 128, 1), blk, 0, stream>>>(
        att, D, WT + (size_t)3 * D * D, D, out, D, bd, D);
}